// Round 13
// baseline (296.989 us; speedup 1.0000x reference)
//
#include <hip/hip_runtime.h>
#include <math.h>

#define NN 20480
#define NE 327680
#define NBATCH 16

typedef float v2f __attribute__((ext_vector_type(2)));

static __device__ __forceinline__ v2f vmax0(v2f a) {
  return __builtin_elementwise_max(a, (v2f){0.f, 0.f});
}
#define VMAX0 vmax0

// ---------------- prep: histogram (1280 blk) + embT4 transpose (72 blk) -----
__global__ __launch_bounds__(256) void prep_kernel(
    const int* __restrict__ dst, int* __restrict__ cnt,
    const float* __restrict__ e4, float* __restrict__ t4) {
  int b = blockIdx.x;
  if (b < NE / 256) {
    int e = b * 256 + threadIdx.x;
    atomicAdd(&cnt[dst[e]], 1);
  } else {
    int idx = (b - NE / 256) * 256 + threadIdx.x;   // 0 .. 18431
    int t = idx >> 9, rem = idx & 511;
    int q = rem >> 7, o = (rem >> 1) & 63, r = rem & 1;
    // dest [t][q][o][r]  <-  src emb[t][(2q+r)*64 + o]
    t4[idx] = e4[(t << 9) + (((q << 1) | r) << 6) + o];
  }
}

// ------- exclusive scan (1 block); writes off AND cur; zeroes pool ----------
// Shuffle-based: wave-level __shfl_up scan + wave0 scan of 16 partials,
// 2 barriers total.
__global__ __launch_bounds__(1024) void scan_kernel(const int* __restrict__ cnt,
                                                    int* __restrict__ off,
                                                    int* __restrict__ cur,
                                                    float* __restrict__ poolz) {
  __shared__ int wsum[16];
  int tid = threadIdx.x;
  int lane = tid & 63, wid = tid >> 6;
  if (tid < NBATCH * 64 + NBATCH) poolz[tid] = 0.f;
  const int PT = NN / 1024;              // 20 per thread
  int loc[PT];
  int run = 0;
  int base = tid * PT;
#pragma unroll
  for (int k = 0; k < PT; k++) { loc[k] = run; run += cnt[base + k]; }
  int inc = run;
#pragma unroll
  for (int d = 1; d < 64; d <<= 1) {
    int u = __shfl_up(inc, d);
    if (lane >= d) inc += u;
  }
  if (lane == 63) wsum[wid] = inc;
  __syncthreads();
  if (wid == 0) {
    int v = (lane < 16) ? wsum[lane] : 0;
#pragma unroll
    for (int d = 1; d < 16; d <<= 1) {
      int u = __shfl_up(v, d);
      if (lane >= d) v += u;
    }
    if (lane < 16) wsum[lane] = v;
  }
  __syncthreads();
  int wbase = (wid == 0) ? 0 : wsum[wid - 1];
  int pre = wbase + (inc - run);
#pragma unroll
  for (int k = 0; k < PT; k++) {
    off[base + k] = pre + loc[k];
    cur[base + k] = pre + loc[k];
  }
  if (tid == 1023) off[NN] = wsum[15];   // == NE
}

// ---- scatter (R15: reverted to R13 single-pass — two-pass regressed 9us) ---
__global__ void scatter_kernel(const int* __restrict__ src, const int* __restrict__ dst,
                               const int* __restrict__ etype, const float* __restrict__ eattr,
                               int* __restrict__ cur, float4* __restrict__ es) {
  int e = blockIdx.x * blockDim.x + threadIdx.x;
  if (e >= NE) return;
  int d = dst[e];
  int pos = atomicAdd(&cur[d], 1);
  es[pos] = make_float4(__int_as_float(src[e]), __int_as_float(etype[e]),
                        eattr[2 * e], eattr[2 * e + 1]);
}

// ---------------- fused layer 1 (cin=16, cout=8) — R15 ----------------------
// lane = (esub<<4)|(ihalf<<3)|o. LDS semb with odd stride.
// R15: ONE node per wave (was 2; grid 2560->5120). Node degree is random
// (sigma~4): with multiple nodes/wave the serial chains SUM and the block
// lives until its slowest wave. 1 node/wave quarters per-wave variance.
// rroot moved to epilogue (-8 VGPR in the loop).
__global__ __launch_bounds__(256) void layer_small16(
    const int* __restrict__ off, const float4* __restrict__ es,
    const float* __restrict__ h_in,
    const float* __restrict__ emb, const float* __restrict__ wh,
    const float* __restrict__ bh, const float* __restrict__ wg,
    const float* __restrict__ bg,
    const float* __restrict__ root, const float* __restrict__ bias,
    float* __restrict__ h_out) {
  constexpr int D = 128;
  constexpr int S = D + 1;               // odd stride spreads banks
  __shared__ float semb[36 * S];
  for (int idx = threadIdx.x; idx < 36 * D; idx += 256) {
    int t = idx / D, io = idx - t * D;
    semb[t * S + io] = emb[idx];
  }
  int lane = threadIdx.x & 63;
  int o = lane & 7;
  int ihalf = (lane >> 3) & 1;
  int esub = lane >> 4;                  // 0..3
  int ibase = ihalf * 8;
  v2f rwh0[4], rwh1[4], rbh[4], rwg0[4], rwg1[4], rbg[4];
#pragma unroll
  for (int p = 0; p < 4; p++) {
    int a = (ibase + 2 * p) * 8 + o, b = (ibase + 2 * p + 1) * 8 + o;
    rwh0[p] = (v2f){wh[a], wh[b]};
    rwh1[p] = (v2f){wh[D + a], wh[D + b]};
    rbh[p]  = (v2f){bh[a], bh[b]};
    rwg0[p] = (v2f){wg[a], wg[b]};
    rwg1[p] = (v2f){wg[D + a], wg[D + b]};
    rbg[p]  = (v2f){bg[a], bg[b]};
  }
  float rbias = bias[o];
  __syncthreads();
  int n = __builtin_amdgcn_readfirstlane(blockIdx.x * 4 + (threadIdx.x >> 6));
  int beg = off[n], end = off[n + 1];
  float acc = 0.f;
  for (int j = beg + esub; j < end; j += 4) {
    float4 rec = es[j];
    int s = __float_as_int(rec.x);
    int t = __float_as_int(rec.y);
    v2f ef0 = (v2f){rec.z, rec.z}, ef1 = (v2f){rec.w, rec.w};
    const float4* hp = (const float4*)(h_in + s * 16 + ibase);
    float4 h0 = hp[0], h1 = hp[1];
    v2f hv[4] = {(v2f){h0.x, h0.y}, (v2f){h0.z, h0.w},
                 (v2f){h1.x, h1.y}, (v2f){h1.z, h1.w}};
    const float* st = &semb[t * S + ibase * 8 + o];
    v2f msg = {0.f, 0.f};
#pragma unroll
    for (int p = 0; p < 4; p++) {
      v2f hval = rbh[p] + ef0 * rwh0[p] + ef1 * rwh1[p];   // 2 fma
      v2f gval = rbg[p] + ef0 * rwg0[p] + ef1 * rwg1[p];   // 2 fma
      v2f stv = (v2f){st[(2 * p) * 8], st[(2 * p + 1) * 8]};
      msg += hv[p] * VMAX0(stv * hval + gval);
    }
    acc += msg.x + msg.y;
  }
  // xor8 combines i-halves (same edge), xor16/32 combine edges
  acc += __shfl_xor(acc, 8);
  acc += __shfl_xor(acc, 16);
  acc += __shfl_xor(acc, 32);
  // epilogue: root term (loaded here, off the loop's register budget)
  const float* hn = h_in + n * 16 + ibase;
  v2f rtv = {0.f, 0.f};
#pragma unroll
  for (int p = 0; p < 4; p++) {
    int a = (ibase + 2 * p) * 8 + o, b = (ibase + 2 * p + 1) * 8 + o;
    rtv += (v2f){hn[2 * p], hn[2 * p + 1]} * (v2f){root[a], root[b]};
  }
  float rt = rtv.x + rtv.y;
  rt += __shfl_xor(rt, 8);
  float deg = (float)(end - beg);
  float val = fmaxf(rbias + rt + acc / fmaxf(deg, 1.f), 0.f);
  if (lane < 8) h_out[n * 8 + o] = val;
}

// ---------------- fused layer, cin=8 cout=8 (L2,L3) — R15 -------------------
// lane = (e_sub<<3)|o: 8 edges x 8 outputs. R15: ONE node per wave (was 4;
// grid 1280->5120); rroot in epilogue. Rationale as layer_small16.
__global__ __launch_bounds__(256) void layer_small8(
    const int* __restrict__ off, const float4* __restrict__ es,
    const float* __restrict__ h_in,
    const float* __restrict__ emb, const float* __restrict__ wh,
    const float* __restrict__ bh, const float* __restrict__ wg,
    const float* __restrict__ bg,
    const float* __restrict__ root, const float* __restrict__ bias,
    float* __restrict__ h_out) {
  constexpr int D = 64;
  constexpr int S = D + 1;
  __shared__ float semb[36 * S];
  for (int idx = threadIdx.x; idx < 36 * D; idx += 256) {
    int t = idx / D, io = idx - t * D;
    semb[t * S + io] = emb[idx];
  }
  int lane = threadIdx.x & 63;
  int o = lane & 7, esub = lane >> 3;
  v2f rwh0[4], rwh1[4], rbh[4], rwg0[4], rwg1[4], rbg[4];
#pragma unroll
  for (int p = 0; p < 4; p++) {
    int a = (2 * p) * 8 + o, b = (2 * p + 1) * 8 + o;
    rwh0[p] = (v2f){wh[a], wh[b]};
    rwh1[p] = (v2f){wh[D + a], wh[D + b]};
    rbh[p]  = (v2f){bh[a], bh[b]};
    rwg0[p] = (v2f){wg[a], wg[b]};
    rwg1[p] = (v2f){wg[D + a], wg[D + b]};
    rbg[p]  = (v2f){bg[a], bg[b]};
  }
  float rbias = bias[o];
  __syncthreads();
  int n = __builtin_amdgcn_readfirstlane(blockIdx.x * 4 + (threadIdx.x >> 6));
  int beg = off[n], end = off[n + 1];
  float acc = 0.f;
  for (int j = beg + esub; j < end; j += 8) {
    float4 rec = es[j];
    int s = __float_as_int(rec.x);
    int t = __float_as_int(rec.y);
    v2f ef0 = (v2f){rec.z, rec.z}, ef1 = (v2f){rec.w, rec.w};
    const float4* hp = (const float4*)(h_in + s * 8);
    float4 h0 = hp[0], h1 = hp[1];
    v2f hv[4] = {(v2f){h0.x, h0.y}, (v2f){h0.z, h0.w},
                 (v2f){h1.x, h1.y}, (v2f){h1.z, h1.w}};
    const float* st = &semb[t * S + o];
    v2f msg = {0.f, 0.f};
#pragma unroll
    for (int p = 0; p < 4; p++) {
      v2f hval = rbh[p] + ef0 * rwh0[p] + ef1 * rwh1[p];   // 2 fma
      v2f gval = rbg[p] + ef0 * rwg0[p] + ef1 * rwg1[p];   // 2 fma
      v2f stv = (v2f){st[(2 * p) * 8], st[(2 * p + 1) * 8]};
      msg += hv[p] * VMAX0(stv * hval + gval);
    }
    acc += msg.x + msg.y;
  }
  acc += __shfl_xor(acc, 8);
  acc += __shfl_xor(acc, 16);
  acc += __shfl_xor(acc, 32);
  float deg = (float)(end - beg);
  // epilogue: root term
  const float* hn = h_in + n * 8;
  v2f rtv = {0.f, 0.f};
#pragma unroll
  for (int p = 0; p < 4; p++) {
    int a = (2 * p) * 8 + o, b = (2 * p + 1) * 8 + o;
    rtv += (v2f){hn[2 * p], hn[2 * p + 1]} * (v2f){root[a], root[b]};
  }
  float val = fmaxf(rbias + rtv.x + rtv.y + acc / fmaxf(deg, 1.f), 0.f);
  if (lane < 8) h_out[n * 8 + o] = val;
}

// ---------------- fused layer 4 (cin=8, cout=64) — R12 body (best) ----------
// R10's loop body (1024 thr, 40 nodes/block, 16 waves 8x3+8x2, SGPR es-pair
// prefetch) + R11's fused gated pooling epilogue. 32 blocks per batch.
__global__ __launch_bounds__(1024) void layer_l4(
    const int* __restrict__ off, const float4* __restrict__ es,
    const float* __restrict__ h_in, const float* __restrict__ embT,
    const float* __restrict__ wh, const float* __restrict__ bh,
    const float* __restrict__ wg, const float* __restrict__ bg,
    const float* __restrict__ root, const float* __restrict__ bias,
    const int* __restrict__ ct,
    float* __restrict__ pooled, float* __restrict__ pcnt) {
  __shared__ float semb[36 * 512];                 // 73728 B
  __shared__ float sacc[64];
  __shared__ float scnt;
  for (int idx = threadIdx.x; idx < 36 * 128; idx += 1024)
    ((float4*)semb)[idx] = ((const float4*)embT)[idx];
  if (threadIdx.x < 64) sacc[threadIdx.x] = 0.f;
  if (threadIdx.x == 64) scnt = 0.f;
  int lane = threadIdx.x & 63;
  v2f rwh0[4], rwh1[4], rbh[4], rwg0[4], rwg1[4], rbg[4], rroot[4];
#pragma unroll
  for (int p = 0; p < 4; p++) {
    int a = (2 * p) * 64 + lane, b = (2 * p + 1) * 64 + lane;
    rwh0[p] = (v2f){wh[a], wh[b]};
    rwh1[p] = (v2f){wh[512 + a], wh[512 + b]};
    rbh[p]  = (v2f){bh[a], bh[b]};
    rwg0[p] = (v2f){wg[a], wg[b]};
    rwg1[p] = (v2f){wg[512 + a], wg[512 + b]};
    rbg[p]  = (v2f){bg[a], bg[b]};
    rroot[p] = (v2f){root[a], root[b]};
  }
  float rbias = bias[lane];
  __syncthreads();
  // 16 waves/block, 40 nodes/block: waves 0-7 take 3 nodes, 8-15 take 2.
  int w = __builtin_amdgcn_readfirstlane((int)(threadIdx.x >> 6));
  int blkbase = (int)blockIdx.x * 40;
  int nfirst = (w < 8) ? (blkbase + w * 3) : (blkbase + 24 + (w - 8) * 2);
  int ncnt = (w < 8) ? 3 : 2;
  const float* sl = &semb[lane * 2];               // lane's column base
  for (int k = 0; k < ncnt; k++) {
    int n = nfirst + k;
    int beg = off[n], end = off[n + 1];
    float acc0 = 0.f, acc1 = 0.f;
    int e = beg;
    // prefetch first record pair (wave-uniform -> SGPRs)
    float4 nr0, nr1;
    if (e + 2 <= end) { nr0 = es[e]; nr1 = es[e + 1]; }
    for (; e + 2 <= end; e += 2) {
      float4 r0 = nr0, r1 = nr1;
      // prefetch next pair (clamped so the load is unconditional+valid)
      int pn = (e + 4 <= end) ? (e + 2) : e;
      nr0 = es[pn]; nr1 = es[pn + 1];
      int s0 = __float_as_int(r0.x), t0 = __float_as_int(r0.y);
      int s1 = __float_as_int(r1.x), t1 = __float_as_int(r1.y);
      const float4* hp0 = (const float4*)(h_in + s0 * 8);
      const float4* hp1 = (const float4*)(h_in + s1 * 8);
      float4 a0 = hp0[0], a1 = hp0[1];
      float4 b0 = hp1[0], b1 = hp1[1];
      const float* st0 = sl + t0 * 512;
      const float* st1 = sl + t1 * 512;
      v2f sv0[4], sv1[4];
#pragma unroll
      for (int q = 0; q < 4; q++) {                // 4x ds_read_b64 each
        sv0[q] = *(const v2f*)(st0 + q * 128);
        sv1[q] = *(const v2f*)(st1 + q * 128);
      }
      v2f hva[4] = {(v2f){a0.x, a0.y}, (v2f){a0.z, a0.w},
                    (v2f){a1.x, a1.y}, (v2f){a1.z, a1.w}};
      v2f hvb[4] = {(v2f){b0.x, b0.y}, (v2f){b0.z, b0.w},
                    (v2f){b1.x, b1.y}, (v2f){b1.z, b1.w}};
      v2f e00 = (v2f){r0.z, r0.z}, e01 = (v2f){r0.w, r0.w};
      v2f e10 = (v2f){r1.z, r1.z}, e11 = (v2f){r1.w, r1.w};
      v2f m0 = {0.f, 0.f}, m1 = {0.f, 0.f};
#pragma unroll
      for (int p = 0; p < 4; p++) {
        v2f hv0 = rbh[p] + e00 * rwh0[p] + e01 * rwh1[p];
        v2f gv0 = rbg[p] + e00 * rwg0[p] + e01 * rwg1[p];
        m0 += hva[p] * VMAX0(sv0[p] * hv0 + gv0);
        v2f hv1 = rbh[p] + e10 * rwh0[p] + e11 * rwh1[p];
        v2f gv1 = rbg[p] + e10 * rwg0[p] + e11 * rwg1[p];
        m1 += hvb[p] * VMAX0(sv1[p] * hv1 + gv1);
      }
      acc0 += m0.x + m0.y;
      acc1 += m1.x + m1.y;
    }
    if (e < end) {
      float4 r0 = es[e];
      int s0 = __float_as_int(r0.x), t0 = __float_as_int(r0.y);
      const float4* hp0 = (const float4*)(h_in + s0 * 8);
      float4 a0 = hp0[0], a1 = hp0[1];
      const float* st0 = sl + t0 * 512;
      v2f sv0[4];
#pragma unroll
      for (int q = 0; q < 4; q++) sv0[q] = *(const v2f*)(st0 + q * 128);
      v2f hva[4] = {(v2f){a0.x, a0.y}, (v2f){a0.z, a0.w},
                    (v2f){a1.x, a1.y}, (v2f){a1.z, a1.w}};
      v2f e00 = (v2f){r0.z, r0.z}, e01 = (v2f){r0.w, r0.w};
      v2f m0 = {0.f, 0.f};
#pragma unroll
      for (int p = 0; p < 4; p++) {
        v2f hv0 = rbh[p] + e00 * rwh0[p] + e01 * rwh1[p];
        v2f gv0 = rbg[p] + e00 * rwg0[p] + e01 * rwg1[p];
        m0 += hva[p] * VMAX0(sv0[p] * hv0 + gv0);
      }
      acc0 += m0.x + m0.y;
    }
    float acc = acc0 + acc1;
    float deg = (float)(end - beg);
    const float* hn = h_in + n * 8;
    v2f rtv = {0.f, 0.f};
#pragma unroll
    for (int p = 0; p < 4; p++)
      rtv += (v2f){hn[2 * p], hn[2 * p + 1]} * rroot[p];
    float val = fmaxf(rbias + rtv.x + rtv.y + acc / fmaxf(deg, 1.f), 0.f);
    // fused gated pooling (replaces h4 store; wave-uniform branch)
    if (ct[n] == 1) {
      atomicAdd(&sacc[lane], val);
      if (lane == 0) atomicAdd(&scnt, 1.f);
    }
  }
  __syncthreads();
  int bb = blockIdx.x / 32;                        // 32 blocks per batch
  if (threadIdx.x < 64)
    unsafeAtomicAdd(&pooled[bb * 64 + threadIdx.x], sacc[threadIdx.x]);
  else if (threadIdx.x == 64)
    unsafeAtomicAdd(&pcnt[bb], scnt);
}

// ---------------- pooling phase 2 + classifier + sigmoid (1 block) ----------
__global__ __launch_bounds__(1024) void pool2_kernel(
    const float* __restrict__ pooled, const float* __restrict__ pcnt,
    const float* __restrict__ clf_w, const float* __restrict__ clf_b,
    float* __restrict__ out) {
  int b = threadIdx.x >> 6, o = threadIdx.x & 63;
  float c = pcnt[b];
  float v = (pooled[b * 64 + o] / fmaxf(c, 1.f)) * clf_w[o];
#pragma unroll
  for (int d = 32; d; d >>= 1) v += __shfl_down(v, d);
  if (o == 0) out[b] = 1.f / (1.f + expf(-(v + clf_b[0])));
}

// ---------------------------------------------------------------------------
extern "C" void kernel_launch(void* const* d_in, const int* in_sizes, int n_in,
                              void* d_out, int out_size, void* d_ws, size_t ws_size,
                              hipStream_t stream) {
  (void)in_sizes; (void)n_in; (void)out_size; (void)ws_size;
  const float* x     = (const float*)d_in[0];
  const int*   eidx  = (const int*)d_in[1];
  const int*   src   = eidx;
  const int*   dst   = eidx + NE;
  const int*   etype = (const int*)d_in[2];
  const float* eattr = (const float*)d_in[3];
  const int*   ct    = (const int*)d_in[4];
  const float *emb[4], *wh[4], *bh[4], *wg[4], *bg[4], *root[4], *bias[4];
  for (int l = 0; l < 4; l++) {
    int b0 = 6 + 7 * l;
    emb[l]  = (const float*)d_in[b0 + 0];
    wh[l]   = (const float*)d_in[b0 + 1];
    bh[l]   = (const float*)d_in[b0 + 2];
    wg[l]   = (const float*)d_in[b0 + 3];
    bg[l]   = (const float*)d_in[b0 + 4];
    root[l] = (const float*)d_in[b0 + 5];
    bias[l] = (const float*)d_in[b0 + 6];
  }
  const float* clf_w = (const float*)d_in[34];
  const float* clf_b = (const float*)d_in[35];
  float* outp = (float*)d_out;

  // workspace layout (floats): ~11.96 MB
  float* ws  = (float*)d_ws;
  int*    off    = (int*)ws;                      // NN+1 (pad 20484)
  float4* es     = (float4*)(ws + 20484);         // NE float4
  float*  hA     = ws + 20484 + 4 * NE;           // 8N
  float*  hB     = hA + 8 * NN;                   // 8N
  float*  scratch= hB + 8 * NN;                   // cnt/cur alias region
  float*  embT4  = scratch + 64 * NN;             // 36*512
  float*  pooled = embT4 + 36 * 512;              // 16*64
  float*  pcnt   = pooled + 16 * 64;              // 16
  int*    cnt    = (int*)scratch;                 // alias (dead after scan)
  int*    cur    = cnt + NN;                      // alias

  // ---- CSR build + embT4 transpose (4 dispatches) ----
  hipMemsetAsync(cnt, 0, NN * sizeof(int), stream);
  prep_kernel<<<NE / 256 + 72, 256, 0, stream>>>(dst, cnt, emb[3], embT4);
  scan_kernel<<<1, 1024, 0, stream>>>(cnt, off, cur, pooled);
  scatter_kernel<<<NE / 256, 256, 0, stream>>>(src, dst, etype, eattr, cur, es);

  // ---- 4 fused layers (L4 also does the gated pooling) ----
  layer_small16<<<NN / 4, 256, 0, stream>>>(off, es, x,
      emb[0], wh[0], bh[0], wg[0], bg[0], root[0], bias[0], hA);
  layer_small8<<<NN / 4, 256, 0, stream>>>(off, es, hA,
      emb[1], wh[1], bh[1], wg[1], bg[1], root[1], bias[1], hB);
  layer_small8<<<NN / 4, 256, 0, stream>>>(off, es, hB,
      emb[2], wh[2], bh[2], wg[2], bg[2], root[2], bias[2], hA);
  layer_l4<<<NN / 40, 1024, 0, stream>>>(off, es, hA, embT4,
      wh[3], bh[3], wg[3], bg[3], root[3], bias[3], ct, pooled, pcnt);

  // ---- classifier + sigmoid ----
  pool2_kernel<<<1, 1024, 0, stream>>>(pooled, pcnt, clf_w, clf_b, outp);
}

// Round 14
// 276.603 us; speedup vs baseline: 1.0737x; 1.0737x over previous
//
#include <hip/hip_runtime.h>
#include <math.h>

#define NN 20480
#define NE 327680
#define NBATCH 16

typedef float v2f __attribute__((ext_vector_type(2)));

static __device__ __forceinline__ v2f vmax0(v2f a) {
  return __builtin_elementwise_max(a, (v2f){0.f, 0.f});
}
#define VMAX0 vmax0

// ---------------- prep: histogram (1280 blk) + embT4 transpose (72 blk) -----
__global__ __launch_bounds__(256) void prep_kernel(
    const int* __restrict__ dst, int* __restrict__ cnt,
    const float* __restrict__ e4, float* __restrict__ t4) {
  int b = blockIdx.x;
  if (b < NE / 256) {
    int e = b * 256 + threadIdx.x;
    atomicAdd(&cnt[dst[e]], 1);
  } else {
    int idx = (b - NE / 256) * 256 + threadIdx.x;   // 0 .. 18431
    int t = idx >> 9, rem = idx & 511;
    int q = rem >> 7, o = (rem >> 1) & 63, r = rem & 1;
    // dest [t][q][o][r]  <-  src emb[t][(2q+r)*64 + o]
    t4[idx] = e4[(t << 9) + (((q << 1) | r) << 6) + o];
  }
}

// ------- exclusive scan (1 block); writes off AND cur; zeroes pool ----------
// Shuffle-based: wave-level __shfl_up scan + wave0 scan of 16 partials,
// 2 barriers total.
__global__ __launch_bounds__(1024) void scan_kernel(const int* __restrict__ cnt,
                                                    int* __restrict__ off,
                                                    int* __restrict__ cur,
                                                    float* __restrict__ poolz) {
  __shared__ int wsum[16];
  int tid = threadIdx.x;
  int lane = tid & 63, wid = tid >> 6;
  if (tid < NBATCH * 64 + NBATCH) poolz[tid] = 0.f;
  const int PT = NN / 1024;              // 20 per thread
  int loc[PT];
  int run = 0;
  int base = tid * PT;
#pragma unroll
  for (int k = 0; k < PT; k++) { loc[k] = run; run += cnt[base + k]; }
  int inc = run;
#pragma unroll
  for (int d = 1; d < 64; d <<= 1) {
    int u = __shfl_up(inc, d);
    if (lane >= d) inc += u;
  }
  if (lane == 63) wsum[wid] = inc;
  __syncthreads();
  if (wid == 0) {
    int v = (lane < 16) ? wsum[lane] : 0;
#pragma unroll
    for (int d = 1; d < 16; d <<= 1) {
      int u = __shfl_up(v, d);
      if (lane >= d) v += u;
    }
    if (lane < 16) wsum[lane] = v;
  }
  __syncthreads();
  int wbase = (wid == 0) ? 0 : wsum[wid - 1];
  int pre = wbase + (inc - run);
#pragma unroll
  for (int k = 0; k < PT; k++) {
    off[base + k] = pre + loc[k];
    cur[base + k] = pre + loc[k];
  }
  if (tid == 1023) off[NN] = wsum[15];   // == NE
}

// ---- scatter (single-pass; R14's two-pass split regressed 9us) -------------
__global__ void scatter_kernel(const int* __restrict__ src, const int* __restrict__ dst,
                               const int* __restrict__ etype, const float* __restrict__ eattr,
                               int* __restrict__ cur, float4* __restrict__ es) {
  int e = blockIdx.x * blockDim.x + threadIdx.x;
  if (e >= NE) return;
  int d = dst[e];
  int pos = atomicAdd(&cur[d], 1);
  es[pos] = make_float4(__int_as_float(src[e]), __int_as_float(etype[e]),
                        eattr[2 * e], eattr[2 * e + 1]);
}

// ---------------- fused layer 1 (cin=16, cout=8) — R13 geometry -------------
// lane = (esub<<4)|(ihalf<<3)|o. LDS semb with odd stride. 2 nodes/wave.
// R16: semb staging via float4 global loads (4x fewer load insts; LDS writes
// stay scalar because the odd stride S=D+1 forbids b128 stores).
__global__ __launch_bounds__(256) void layer_small16(
    const int* __restrict__ off, const float4* __restrict__ es,
    const float* __restrict__ h_in,
    const float* __restrict__ emb, const float* __restrict__ wh,
    const float* __restrict__ bh, const float* __restrict__ wg,
    const float* __restrict__ bg,
    const float* __restrict__ root, const float* __restrict__ bias,
    float* __restrict__ h_out) {
  constexpr int D = 128;
  constexpr int S = D + 1;               // odd stride spreads banks
  __shared__ float semb[36 * S];
  for (int i4 = threadIdx.x; i4 < 36 * D / 4; i4 += 256) {
    int idx = i4 * 4;
    int t = idx >> 7, io = idx & 127;    // D=128; float4 never crosses a row
    float4 v = ((const float4*)emb)[i4];
    float* p = &semb[t * S + io];
    p[0] = v.x; p[1] = v.y; p[2] = v.z; p[3] = v.w;
  }
  int lane = threadIdx.x & 63;
  int o = lane & 7;
  int ihalf = (lane >> 3) & 1;
  int esub = lane >> 4;                  // 0..3
  int ibase = ihalf * 8;
  v2f rwh0[4], rwh1[4], rbh[4], rwg0[4], rwg1[4], rbg[4], rroot[4];
#pragma unroll
  for (int p = 0; p < 4; p++) {
    int a = (ibase + 2 * p) * 8 + o, b = (ibase + 2 * p + 1) * 8 + o;
    rwh0[p] = (v2f){wh[a], wh[b]};
    rwh1[p] = (v2f){wh[D + a], wh[D + b]};
    rbh[p]  = (v2f){bh[a], bh[b]};
    rwg0[p] = (v2f){wg[a], wg[b]};
    rwg1[p] = (v2f){wg[D + a], wg[D + b]};
    rbg[p]  = (v2f){bg[a], bg[b]};
    rroot[p] = (v2f){root[a], root[b]};
  }
  float rbias = bias[o];
  __syncthreads();
  int wid = __builtin_amdgcn_readfirstlane(blockIdx.x * 4 + (threadIdx.x >> 6));
  for (int k = 0; k < 2; k++) {
    int n = wid * 2 + k;
    int beg = off[n], end = off[n + 1];
    float acc = 0.f;
    for (int j = beg + esub; j < end; j += 4) {
      float4 rec = es[j];
      int s = __float_as_int(rec.x);
      int t = __float_as_int(rec.y);
      v2f ef0 = (v2f){rec.z, rec.z}, ef1 = (v2f){rec.w, rec.w};
      const float4* hp = (const float4*)(h_in + s * 16 + ibase);
      float4 h0 = hp[0], h1 = hp[1];
      v2f hv[4] = {(v2f){h0.x, h0.y}, (v2f){h0.z, h0.w},
                   (v2f){h1.x, h1.y}, (v2f){h1.z, h1.w}};
      const float* st = &semb[t * S + ibase * 8 + o];
      v2f msg = {0.f, 0.f};
#pragma unroll
      for (int p = 0; p < 4; p++) {
        v2f hval = rbh[p] + ef0 * rwh0[p] + ef1 * rwh1[p];   // 2 fma
        v2f gval = rbg[p] + ef0 * rwg0[p] + ef1 * rwg1[p];   // 2 fma
        v2f stv = (v2f){st[(2 * p) * 8], st[(2 * p + 1) * 8]};
        msg += hv[p] * VMAX0(stv * hval + gval);
      }
      acc += msg.x + msg.y;
    }
    // xor8 combines i-halves (same edge), xor16/32 combine edges
    acc += __shfl_xor(acc, 8);
    acc += __shfl_xor(acc, 16);
    acc += __shfl_xor(acc, 32);
    const float* hn = h_in + n * 16 + ibase;
    v2f rtv = {0.f, 0.f};
#pragma unroll
    for (int p = 0; p < 4; p++)
      rtv += (v2f){hn[2 * p], hn[2 * p + 1]} * rroot[p];
    float rt = rtv.x + rtv.y;
    rt += __shfl_xor(rt, 8);
    float deg = (float)(end - beg);
    float val = fmaxf(rbias + rt + acc / fmaxf(deg, 1.f), 0.f);
    if (lane < 8) h_out[n * 8 + o] = val;
  }
}

// ---------------- fused layer, cin=8 cout=8 (L2,L3) — R13 geometry ----------
// lane = (e_sub<<3)|o: 8 edges x 8 outputs. 4 nodes per wave. LDS semb.
// R16: float4 semb staging (see layer_small16).
__global__ __launch_bounds__(256) void layer_small8(
    const int* __restrict__ off, const float4* __restrict__ es,
    const float* __restrict__ h_in,
    const float* __restrict__ emb, const float* __restrict__ wh,
    const float* __restrict__ bh, const float* __restrict__ wg,
    const float* __restrict__ bg,
    const float* __restrict__ root, const float* __restrict__ bias,
    float* __restrict__ h_out) {
  constexpr int D = 64;
  constexpr int S = D + 1;
  __shared__ float semb[36 * S];
  for (int i4 = threadIdx.x; i4 < 36 * D / 4; i4 += 256) {
    int idx = i4 * 4;
    int t = idx >> 6, io = idx & 63;     // D=64; float4 never crosses a row
    float4 v = ((const float4*)emb)[i4];
    float* p = &semb[t * S + io];
    p[0] = v.x; p[1] = v.y; p[2] = v.z; p[3] = v.w;
  }
  int lane = threadIdx.x & 63;
  int o = lane & 7, esub = lane >> 3;
  v2f rwh0[4], rwh1[4], rbh[4], rwg0[4], rwg1[4], rbg[4], rroot[4];
#pragma unroll
  for (int p = 0; p < 4; p++) {
    int a = (2 * p) * 8 + o, b = (2 * p + 1) * 8 + o;
    rwh0[p] = (v2f){wh[a], wh[b]};
    rwh1[p] = (v2f){wh[D + a], wh[D + b]};
    rbh[p]  = (v2f){bh[a], bh[b]};
    rwg0[p] = (v2f){wg[a], wg[b]};
    rwg1[p] = (v2f){wg[D + a], wg[D + b]};
    rbg[p]  = (v2f){bg[a], bg[b]};
    rroot[p] = (v2f){root[a], root[b]};
  }
  float rbias = bias[o];
  __syncthreads();
  int wid = __builtin_amdgcn_readfirstlane(blockIdx.x * 4 + (threadIdx.x >> 6));
  for (int k = 0; k < 4; k++) {
    int n = wid * 4 + k;
    int beg = off[n], end = off[n + 1];
    float acc = 0.f;
    for (int j = beg + esub; j < end; j += 8) {
      float4 rec = es[j];
      int s = __float_as_int(rec.x);
      int t = __float_as_int(rec.y);
      v2f ef0 = (v2f){rec.z, rec.z}, ef1 = (v2f){rec.w, rec.w};
      const float4* hp = (const float4*)(h_in + s * 8);
      float4 h0 = hp[0], h1 = hp[1];
      v2f hv[4] = {(v2f){h0.x, h0.y}, (v2f){h0.z, h0.w},
                   (v2f){h1.x, h1.y}, (v2f){h1.z, h1.w}};
      const float* st = &semb[t * S + o];
      v2f msg = {0.f, 0.f};
#pragma unroll
      for (int p = 0; p < 4; p++) {
        v2f hval = rbh[p] + ef0 * rwh0[p] + ef1 * rwh1[p];   // 2 fma
        v2f gval = rbg[p] + ef0 * rwg0[p] + ef1 * rwg1[p];   // 2 fma
        v2f stv = (v2f){st[(2 * p) * 8], st[(2 * p + 1) * 8]};
        msg += hv[p] * VMAX0(stv * hval + gval);
      }
      acc += msg.x + msg.y;
    }
    acc += __shfl_xor(acc, 8);
    acc += __shfl_xor(acc, 16);
    acc += __shfl_xor(acc, 32);
    float deg = (float)(end - beg);
    const float* hn = h_in + n * 8;
    v2f rtv = {0.f, 0.f};
#pragma unroll
    for (int p = 0; p < 4; p++)
      rtv += (v2f){hn[2 * p], hn[2 * p + 1]} * rroot[p];
    float val = fmaxf(rbias + rtv.x + rtv.y + acc / fmaxf(deg, 1.f), 0.f);
    if (lane < 8) h_out[n * 8 + o] = val;
  }
}

// ---------------- fused layer 4 (cin=8, cout=64) — R12 body (best) ----------
// R10's loop body (1024 thr, 40 nodes/block, 16 waves 8x3+8x2, SGPR es-pair
// prefetch) + R11's fused gated pooling epilogue. 32 blocks per batch.
__global__ __launch_bounds__(1024) void layer_l4(
    const int* __restrict__ off, const float4* __restrict__ es,
    const float* __restrict__ h_in, const float* __restrict__ embT,
    const float* __restrict__ wh, const float* __restrict__ bh,
    const float* __restrict__ wg, const float* __restrict__ bg,
    const float* __restrict__ root, const float* __restrict__ bias,
    const int* __restrict__ ct,
    float* __restrict__ pooled, float* __restrict__ pcnt) {
  __shared__ float semb[36 * 512];                 // 73728 B
  __shared__ float sacc[64];
  __shared__ float scnt;
  for (int idx = threadIdx.x; idx < 36 * 128; idx += 1024)
    ((float4*)semb)[idx] = ((const float4*)embT)[idx];
  if (threadIdx.x < 64) sacc[threadIdx.x] = 0.f;
  if (threadIdx.x == 64) scnt = 0.f;
  int lane = threadIdx.x & 63;
  v2f rwh0[4], rwh1[4], rbh[4], rwg0[4], rwg1[4], rbg[4], rroot[4];
#pragma unroll
  for (int p = 0; p < 4; p++) {
    int a = (2 * p) * 64 + lane, b = (2 * p + 1) * 64 + lane;
    rwh0[p] = (v2f){wh[a], wh[b]};
    rwh1[p] = (v2f){wh[512 + a], wh[512 + b]};
    rbh[p]  = (v2f){bh[a], bh[b]};
    rwg0[p] = (v2f){wg[a], wg[b]};
    rwg1[p] = (v2f){wg[512 + a], wg[512 + b]};
    rbg[p]  = (v2f){bg[a], bg[b]};
    rroot[p] = (v2f){root[a], root[b]};
  }
  float rbias = bias[lane];
  __syncthreads();
  // 16 waves/block, 40 nodes/block: waves 0-7 take 3 nodes, 8-15 take 2.
  int w = __builtin_amdgcn_readfirstlane((int)(threadIdx.x >> 6));
  int blkbase = (int)blockIdx.x * 40;
  int nfirst = (w < 8) ? (blkbase + w * 3) : (blkbase + 24 + (w - 8) * 2);
  int ncnt = (w < 8) ? 3 : 2;
  const float* sl = &semb[lane * 2];               // lane's column base
  for (int k = 0; k < ncnt; k++) {
    int n = nfirst + k;
    int beg = off[n], end = off[n + 1];
    float acc0 = 0.f, acc1 = 0.f;
    int e = beg;
    // prefetch first record pair (wave-uniform -> SGPRs)
    float4 nr0, nr1;
    if (e + 2 <= end) { nr0 = es[e]; nr1 = es[e + 1]; }
    for (; e + 2 <= end; e += 2) {
      float4 r0 = nr0, r1 = nr1;
      // prefetch next pair (clamped so the load is unconditional+valid)
      int pn = (e + 4 <= end) ? (e + 2) : e;
      nr0 = es[pn]; nr1 = es[pn + 1];
      int s0 = __float_as_int(r0.x), t0 = __float_as_int(r0.y);
      int s1 = __float_as_int(r1.x), t1 = __float_as_int(r1.y);
      const float4* hp0 = (const float4*)(h_in + s0 * 8);
      const float4* hp1 = (const float4*)(h_in + s1 * 8);
      float4 a0 = hp0[0], a1 = hp0[1];
      float4 b0 = hp1[0], b1 = hp1[1];
      const float* st0 = sl + t0 * 512;
      const float* st1 = sl + t1 * 512;
      v2f sv0[4], sv1[4];
#pragma unroll
      for (int q = 0; q < 4; q++) {                // 4x ds_read_b64 each
        sv0[q] = *(const v2f*)(st0 + q * 128);
        sv1[q] = *(const v2f*)(st1 + q * 128);
      }
      v2f hva[4] = {(v2f){a0.x, a0.y}, (v2f){a0.z, a0.w},
                    (v2f){a1.x, a1.y}, (v2f){a1.z, a1.w}};
      v2f hvb[4] = {(v2f){b0.x, b0.y}, (v2f){b0.z, b0.w},
                    (v2f){b1.x, b1.y}, (v2f){b1.z, b1.w}};
      v2f e00 = (v2f){r0.z, r0.z}, e01 = (v2f){r0.w, r0.w};
      v2f e10 = (v2f){r1.z, r1.z}, e11 = (v2f){r1.w, r1.w};
      v2f m0 = {0.f, 0.f}, m1 = {0.f, 0.f};
#pragma unroll
      for (int p = 0; p < 4; p++) {
        v2f hv0 = rbh[p] + e00 * rwh0[p] + e01 * rwh1[p];
        v2f gv0 = rbg[p] + e00 * rwg0[p] + e01 * rwg1[p];
        m0 += hva[p] * VMAX0(sv0[p] * hv0 + gv0);
        v2f hv1 = rbh[p] + e10 * rwh0[p] + e11 * rwh1[p];
        v2f gv1 = rbg[p] + e10 * rwg0[p] + e11 * rwg1[p];
        m1 += hvb[p] * VMAX0(sv1[p] * hv1 + gv1);
      }
      acc0 += m0.x + m0.y;
      acc1 += m1.x + m1.y;
    }
    if (e < end) {
      float4 r0 = es[e];
      int s0 = __float_as_int(r0.x), t0 = __float_as_int(r0.y);
      const float4* hp0 = (const float4*)(h_in + s0 * 8);
      float4 a0 = hp0[0], a1 = hp0[1];
      const float* st0 = sl + t0 * 512;
      v2f sv0[4];
#pragma unroll
      for (int q = 0; q < 4; q++) sv0[q] = *(const v2f*)(st0 + q * 128);
      v2f hva[4] = {(v2f){a0.x, a0.y}, (v2f){a0.z, a0.w},
                    (v2f){a1.x, a1.y}, (v2f){a1.z, a1.w}};
      v2f e00 = (v2f){r0.z, r0.z}, e01 = (v2f){r0.w, r0.w};
      v2f m0 = {0.f, 0.f};
#pragma unroll
      for (int p = 0; p < 4; p++) {
        v2f hv0 = rbh[p] + e00 * rwh0[p] + e01 * rwh1[p];
        v2f gv0 = rbg[p] + e00 * rwg0[p] + e01 * rwg1[p];
        m0 += hva[p] * VMAX0(sv0[p] * hv0 + gv0);
      }
      acc0 += m0.x + m0.y;
    }
    float acc = acc0 + acc1;
    float deg = (float)(end - beg);
    const float* hn = h_in + n * 8;
    v2f rtv = {0.f, 0.f};
#pragma unroll
    for (int p = 0; p < 4; p++)
      rtv += (v2f){hn[2 * p], hn[2 * p + 1]} * rroot[p];
    float val = fmaxf(rbias + rtv.x + rtv.y + acc / fmaxf(deg, 1.f), 0.f);
    // fused gated pooling (replaces h4 store; wave-uniform branch)
    if (ct[n] == 1) {
      atomicAdd(&sacc[lane], val);
      if (lane == 0) atomicAdd(&scnt, 1.f);
    }
  }
  __syncthreads();
  int bb = blockIdx.x / 32;                        // 32 blocks per batch
  if (threadIdx.x < 64)
    unsafeAtomicAdd(&pooled[bb * 64 + threadIdx.x], sacc[threadIdx.x]);
  else if (threadIdx.x == 64)
    unsafeAtomicAdd(&pcnt[bb], scnt);
}

// ---------------- pooling phase 2 + classifier + sigmoid (1 block) ----------
__global__ __launch_bounds__(1024) void pool2_kernel(
    const float* __restrict__ pooled, const float* __restrict__ pcnt,
    const float* __restrict__ clf_w, const float* __restrict__ clf_b,
    float* __restrict__ out) {
  int b = threadIdx.x >> 6, o = threadIdx.x & 63;
  float c = pcnt[b];
  float v = (pooled[b * 64 + o] / fmaxf(c, 1.f)) * clf_w[o];
#pragma unroll
  for (int d = 32; d; d >>= 1) v += __shfl_down(v, d);
  if (o == 0) out[b] = 1.f / (1.f + expf(-(v + clf_b[0])));
}

// ---------------------------------------------------------------------------
extern "C" void kernel_launch(void* const* d_in, const int* in_sizes, int n_in,
                              void* d_out, int out_size, void* d_ws, size_t ws_size,
                              hipStream_t stream) {
  (void)in_sizes; (void)n_in; (void)out_size; (void)ws_size;
  const float* x     = (const float*)d_in[0];
  const int*   eidx  = (const int*)d_in[1];
  const int*   src   = eidx;
  const int*   dst   = eidx + NE;
  const int*   etype = (const int*)d_in[2];
  const float* eattr = (const float*)d_in[3];
  const int*   ct    = (const int*)d_in[4];
  const float *emb[4], *wh[4], *bh[4], *wg[4], *bg[4], *root[4], *bias[4];
  for (int l = 0; l < 4; l++) {
    int b0 = 6 + 7 * l;
    emb[l]  = (const float*)d_in[b0 + 0];
    wh[l]   = (const float*)d_in[b0 + 1];
    bh[l]   = (const float*)d_in[b0 + 2];
    wg[l]   = (const float*)d_in[b0 + 3];
    bg[l]   = (const float*)d_in[b0 + 4];
    root[l] = (const float*)d_in[b0 + 5];
    bias[l] = (const float*)d_in[b0 + 6];
  }
  const float* clf_w = (const float*)d_in[34];
  const float* clf_b = (const float*)d_in[35];
  float* outp = (float*)d_out;

  // workspace layout (floats): ~11.96 MB
  float* ws  = (float*)d_ws;
  int*    off    = (int*)ws;                      // NN+1 (pad 20484)
  float4* es     = (float4*)(ws + 20484);         // NE float4
  float*  hA     = ws + 20484 + 4 * NE;           // 8N
  float*  hB     = hA + 8 * NN;                   // 8N
  float*  scratch= hB + 8 * NN;                   // cnt/cur alias region
  float*  embT4  = scratch + 64 * NN;             // 36*512
  float*  pooled = embT4 + 36 * 512;              // 16*64
  float*  pcnt   = pooled + 16 * 64;              // 16
  int*    cnt    = (int*)scratch;                 // alias (dead after scan)
  int*    cur    = cnt + NN;                      // alias

  // ---- CSR build + embT4 transpose (4 dispatches) ----
  hipMemsetAsync(cnt, 0, NN * sizeof(int), stream);
  prep_kernel<<<NE / 256 + 72, 256, 0, stream>>>(dst, cnt, emb[3], embT4);
  scan_kernel<<<1, 1024, 0, stream>>>(cnt, off, cur, pooled);
  scatter_kernel<<<NE / 256, 256, 0, stream>>>(src, dst, etype, eattr, cur, es);

  // ---- 4 fused layers (L4 also does the gated pooling) ----
  layer_small16<<<2560, 256, 0, stream>>>(off, es, x,
      emb[0], wh[0], bh[0], wg[0], bg[0], root[0], bias[0], hA);
  layer_small8<<<1280, 256, 0, stream>>>(off, es, hA,
      emb[1], wh[1], bh[1], wg[1], bg[1], root[1], bias[1], hB);
  layer_small8<<<1280, 256, 0, stream>>>(off, es, hB,
      emb[2], wh[2], bh[2], wg[2], bg[2], root[2], bias[2], hA);
  layer_l4<<<NN / 40, 1024, 0, stream>>>(off, es, hA, embT4,
      wh[3], bh[3], wg[3], bg[3], root[3], bias[3], ct, pooled, pcnt);

  // ---- classifier + sigmoid ----
  pool2_kernel<<<1, 1024, 0, stream>>>(pooled, pcnt, clf_w, clf_b, outp);
}